// Round 9
// baseline (199.930 us; speedup 1.0000x reference)
//
#include <hip/hip_runtime.h>
#include <math.h>

typedef unsigned short u16;
typedef unsigned int u32;

#define KNBR 32

__device__ __forceinline__ float bf2f(u16 u) { return __uint_as_float((u32)u << 16); }
__device__ __forceinline__ float bflo(u32 u) { return __uint_as_float(u << 16); }
__device__ __forceinline__ float bfhi(u32 u) { return __uint_as_float(u & 0xffff0000u); }
__device__ __forceinline__ u16 f2bf(float f) {
    u32 u = __float_as_uint(f);
    return (u16)((u + 0x7fffu + ((u >> 16) & 1u)) >> 16);
}
__device__ __forceinline__ u32 pk2(float a, float b) {
    return (u32)f2bf(a) | ((u32)f2bf(b) << 16);
}
__device__ __forceinline__ float leaky(float v) { return v >= 0.f ? v : 0.1f * v; }
__device__ __forceinline__ float sigm(float v) { return 1.f / (1.f + expf(-v)); }

// XCD-batch swizzle: blocks land on XCD (blockIdx % 8); give each XCD pair one
// batch so the 2 MB P01/P2 batch segment stays resident in that pair's L2s.
// full=1 only when PN==32768 (4 batches, 64-pt blocks, grid 512).
__device__ __forceinline__ int swz_plb(int b, int full) {
    if (!full) return b << 6;
    int xcd = b & 7;
    int within = ((b >> 3) << 1) | (xcd & 1);      // 0..127
    return ((xcd >> 1) << 13) + (within << 6);     // batch*8192 + within*64
}

// W1: [3][131][64] fp32 (g*8384 + c*64 + d), b1: [3][64],
// W2/W3: [3][64][64] (g*4096 + c*64 + d), b2/b3: [3][64].
// P01: u32 rows of 64 (channel d holds pk2(gate0, gate1)).

// ---------------- K_A: layer-1 preact, gates 0+1 ----------------
// 64-pt block, 8 waves; thread tile 2 pts x 4 ch x 2 gates.
__global__ __launch_bounds__(512) void k_gemm_p01(
    const float* __restrict__ h, const float* __restrict__ x,
    const float* __restrict__ W1f, const float* __restrict__ b1f,
    u32* __restrict__ P01, int p0, int full)
{
    __shared__ u32 a_lds[64 * 65];
    __shared__ float w_lds[2][64 * 64];
    int t = threadIdx.x;
    int plb = swz_plb(blockIdx.x, full);
    int pgb = p0 + plb;
    for (int i = 0; i < 8; ++i) {
        int id = t + i * 512;               // 0..4095
        int p = id >> 6, cw = id & 63;
        const float* src = (cw < 32) ? (h + (size_t)(pgb + p) * 64 + cw * 2)
                                     : (x + (size_t)(pgb + p) * 64 + (cw - 32) * 2);
        float2 v = *(const float2*)src;
        a_lds[p * 65 + cw] = pk2(v.x, v.y);
    }
    int lane = t & 63;
    int cg = __builtin_amdgcn_readfirstlane(t >> 6);   // 0..7
    int di = lane & 15, pi = lane >> 4;
    int pt0 = cg * 8 + pi * 2;
    int dch = di * 4;
    float acc0[2][4], acc1[2][4];
    float4 bv0 = *(const float4*)&b1f[dch];
    float4 bv1 = *(const float4*)&b1f[64 + dch];
    #pragma unroll
    for (int pp = 0; pp < 2; ++pp) {
        acc0[pp][0] = bv0.x; acc0[pp][1] = bv0.y; acc0[pp][2] = bv0.z; acc0[pp][3] = bv0.w;
        acc1[pp][0] = bv1.x; acc1[pp][1] = bv1.y; acc1[pp][2] = bv1.z; acc1[pp][3] = bv1.w;
    }
    for (int half = 0; half < 2; ++half) {
        __syncthreads();
        for (int i = 0; i < 4; ++i) {       // 2048 float4 of weights
            int id = t + i * 512;
            int g = id >> 10, r = (id >> 4) & 63, d4 = id & 15;
            *(float4*)&w_lds[g][r * 64 + d4 * 4] =
                *(const float4*)(W1f + g * 8384 + (half * 64 + r) * 64 + d4 * 4);
        }
        __syncthreads();
        #pragma unroll 4
        for (int cw = 0; cw < 32; ++cw) {
            u32 aw0 = a_lds[(pt0 + 0) * 65 + half * 32 + cw];
            u32 aw1 = a_lds[(pt0 + 1) * 65 + half * 32 + cw];
            float4 wa0 = *(float4*)&w_lds[0][(2 * cw) * 64 + dch];
            float4 wa1 = *(float4*)&w_lds[0][(2 * cw + 1) * 64 + dch];
            float4 wb0 = *(float4*)&w_lds[1][(2 * cw) * 64 + dch];
            float4 wb1 = *(float4*)&w_lds[1][(2 * cw + 1) * 64 + dch];
            float a00 = bflo(aw0), a01 = bfhi(aw0);
            float a10 = bflo(aw1), a11 = bfhi(aw1);
            acc0[0][0] = fmaf(a00, wa0.x, acc0[0][0]); acc0[0][1] = fmaf(a00, wa0.y, acc0[0][1]);
            acc0[0][2] = fmaf(a00, wa0.z, acc0[0][2]); acc0[0][3] = fmaf(a00, wa0.w, acc0[0][3]);
            acc0[0][0] = fmaf(a01, wa1.x, acc0[0][0]); acc0[0][1] = fmaf(a01, wa1.y, acc0[0][1]);
            acc0[0][2] = fmaf(a01, wa1.z, acc0[0][2]); acc0[0][3] = fmaf(a01, wa1.w, acc0[0][3]);
            acc0[1][0] = fmaf(a10, wa0.x, acc0[1][0]); acc0[1][1] = fmaf(a10, wa0.y, acc0[1][1]);
            acc0[1][2] = fmaf(a10, wa0.z, acc0[1][2]); acc0[1][3] = fmaf(a10, wa0.w, acc0[1][3]);
            acc0[1][0] = fmaf(a11, wa1.x, acc0[1][0]); acc0[1][1] = fmaf(a11, wa1.y, acc0[1][1]);
            acc0[1][2] = fmaf(a11, wa1.z, acc0[1][2]); acc0[1][3] = fmaf(a11, wa1.w, acc0[1][3]);
            acc1[0][0] = fmaf(a00, wb0.x, acc1[0][0]); acc1[0][1] = fmaf(a00, wb0.y, acc1[0][1]);
            acc1[0][2] = fmaf(a00, wb0.z, acc1[0][2]); acc1[0][3] = fmaf(a00, wb0.w, acc1[0][3]);
            acc1[0][0] = fmaf(a01, wb1.x, acc1[0][0]); acc1[0][1] = fmaf(a01, wb1.y, acc1[0][1]);
            acc1[0][2] = fmaf(a01, wb1.z, acc1[0][2]); acc1[0][3] = fmaf(a01, wb1.w, acc1[0][3]);
            acc1[1][0] = fmaf(a10, wb0.x, acc1[1][0]); acc1[1][1] = fmaf(a10, wb0.y, acc1[1][1]);
            acc1[1][2] = fmaf(a10, wb0.z, acc1[1][2]); acc1[1][3] = fmaf(a10, wb0.w, acc1[1][3]);
            acc1[1][0] = fmaf(a11, wb1.x, acc1[1][0]); acc1[1][1] = fmaf(a11, wb1.y, acc1[1][1]);
            acc1[1][2] = fmaf(a11, wb1.z, acc1[1][2]); acc1[1][3] = fmaf(a11, wb1.w, acc1[1][3]);
        }
    }
    #pragma unroll
    for (int pp = 0; pp < 2; ++pp) {
        u32 o[4];
        #pragma unroll
        for (int j = 0; j < 4; ++j) o[j] = pk2(acc0[pp][j], acc1[pp][j]);
        *(uint4*)(P01 + (size_t)(plb + pt0 + pp) * 64 + dch) = *(uint4*)o;
    }
}

// ---------------- K_B: pool01 + mlp01 + gemm_p2 fused ----------------
__global__ __launch_bounds__(512) void k_fuse01(
    const u32* __restrict__ P01, const float* __restrict__ W1f,
    const int* __restrict__ nidx, const float* __restrict__ ef,
    const float* __restrict__ h, const float* __restrict__ x,
    const float* __restrict__ W2f, const float* __restrict__ b2f,
    const float* __restrict__ W3f, const float* __restrict__ b3f,
    const float* __restrict__ b1f,
    u16* __restrict__ Z, u16* __restrict__ P2, int p0, int full)
{
    __shared__ u32 a_lds[64 * 65];
    __shared__ float w_lds[2][64 * 64];
    int t = threadIdx.x;
    int plb = swz_plb(blockIdx.x, full);
    int lane = t & 63;
    int cg = __builtin_amdgcn_readfirstlane(t >> 6);   // 0..7

    for (int i = 0; i < 4; ++i) {           // stage W2 (both gates)
        int id = t + i * 512;
        int g = id >> 10, r = (id >> 4) & 63, d4 = id & 15;
        *(float4*)&w_lds[g][r * 64 + d4 * 4] =
            *(const float4*)(W2f + g * 4096 + r * 64 + d4 * 4);
    }
    {
        u16* y16 = (u16*)a_lds;
        float w00 = W1f[8192 + lane], w01 = W1f[8256 + lane], w02 = W1f[8320 + lane];
        float w10 = W1f[16576 + lane], w11 = W1f[16640 + lane], w12 = W1f[16704 + lane];
        for (int pp = 0; pp < 8; ++pp) {
            int lp = cg * 8 + pp;
            int pg = p0 + plb + lp;
            int rbase = ((pg >> 13) << 13) - p0;
            const int* ni = nidx + (size_t)pg * KNBR;
            const float* ep = ef + (size_t)pg * KNBR * 3;
            float m0 = -1e30f, m1 = -1e30f;
            #pragma unroll 16
            for (int k = 0; k < KNBR; ++k) {
                int lr = rbase + ni[k];
                u32 g = P01[(size_t)lr * 64 + lane];
                float e0 = ep[3 * k], e1 = ep[3 * k + 1], e2 = ep[3 * k + 2];
                m0 = fmaxf(m0, bflo(g) + e0 * w00 + e1 * w01 + e2 * w02);
                m1 = fmaxf(m1, bfhi(g) + e0 * w10 + e1 * w11 + e2 * w12);
            }
            y16[lp * 130 + lane]      = f2bf(leaky(m0));
            y16[lp * 130 + 64 + lane] = f2bf(leaky(m1));
        }
    }
    __syncthreads();
    int g = cg >> 2, q = cg & 3;
    int di = lane & 15, pi = lane >> 4;
    int pt0 = q * 16 + pi * 4;
    int dch = di * 4;
    float acc[4][4];
    {
        float4 bv = *(const float4*)&b2f[g * 64 + dch];
        #pragma unroll
        for (int pp = 0; pp < 4; ++pp) {
            acc[pp][0] = bv.x; acc[pp][1] = bv.y; acc[pp][2] = bv.z; acc[pp][3] = bv.w;
        }
    }
    #pragma unroll 2
    for (int cw = 0; cw < 32; ++cw) {
        u32 aw[4];
        #pragma unroll
        for (int pp = 0; pp < 4; ++pp) aw[pp] = a_lds[(pt0 + pp) * 65 + g * 32 + cw];
        float4 w0 = *(float4*)&w_lds[g][(2 * cw) * 64 + dch];
        float4 w1 = *(float4*)&w_lds[g][(2 * cw + 1) * 64 + dch];
        #pragma unroll
        for (int pp = 0; pp < 4; ++pp) {
            float a0 = bflo(aw[pp]), a1 = bfhi(aw[pp]);
            acc[pp][0] = fmaf(a0, w0.x, acc[pp][0]);
            acc[pp][1] = fmaf(a0, w0.y, acc[pp][1]);
            acc[pp][2] = fmaf(a0, w0.z, acc[pp][2]);
            acc[pp][3] = fmaf(a0, w0.w, acc[pp][3]);
            acc[pp][0] = fmaf(a1, w1.x, acc[pp][0]);
            acc[pp][1] = fmaf(a1, w1.y, acc[pp][1]);
            acc[pp][2] = fmaf(a1, w1.z, acc[pp][2]);
            acc[pp][3] = fmaf(a1, w1.w, acc[pp][3]);
        }
    }
    __syncthreads();
    #pragma unroll
    for (int pp = 0; pp < 4; ++pp) {
        int base = (pt0 + pp) * 65 + g * 32 + di * 2;
        a_lds[base]     = pk2(leaky(acc[pp][0]), leaky(acc[pp][1]));
        a_lds[base + 1] = pk2(leaky(acc[pp][2]), leaky(acc[pp][3]));
    }
    for (int i = 0; i < 4; ++i) {           // restage W3
        int id = t + i * 512;
        int gg = id >> 10, r = (id >> 4) & 63, d4 = id & 15;
        *(float4*)&w_lds[gg][r * 64 + d4 * 4] =
            *(const float4*)(W3f + gg * 4096 + r * 64 + d4 * 4);
    }
    __syncthreads();
    {
        float4 bv = *(const float4*)&b3f[g * 64 + dch];
        #pragma unroll
        for (int pp = 0; pp < 4; ++pp) {
            acc[pp][0] = bv.x; acc[pp][1] = bv.y; acc[pp][2] = bv.z; acc[pp][3] = bv.w;
        }
    }
    #pragma unroll 2
    for (int cw = 0; cw < 32; ++cw) {
        u32 aw[4];
        #pragma unroll
        for (int pp = 0; pp < 4; ++pp) aw[pp] = a_lds[(pt0 + pp) * 65 + g * 32 + cw];
        float4 w0 = *(float4*)&w_lds[g][(2 * cw) * 64 + dch];
        float4 w1 = *(float4*)&w_lds[g][(2 * cw + 1) * 64 + dch];
        #pragma unroll
        for (int pp = 0; pp < 4; ++pp) {
            float a0 = bflo(aw[pp]), a1 = bfhi(aw[pp]);
            acc[pp][0] = fmaf(a0, w0.x, acc[pp][0]);
            acc[pp][1] = fmaf(a0, w0.y, acc[pp][1]);
            acc[pp][2] = fmaf(a0, w0.z, acc[pp][2]);
            acc[pp][3] = fmaf(a0, w0.w, acc[pp][3]);
            acc[pp][0] = fmaf(a1, w1.x, acc[pp][0]);
            acc[pp][1] = fmaf(a1, w1.y, acc[pp][1]);
            acc[pp][2] = fmaf(a1, w1.z, acc[pp][2]);
            acc[pp][3] = fmaf(a1, w1.w, acc[pp][3]);
        }
    }
    __syncthreads();
    if (g == 0) {
        #pragma unroll
        for (int pp = 0; pp < 4; ++pp) {
            int pl = plb + pt0 + pp;
            uint2 o;
            o.x = pk2(sigm(acc[pp][0]), sigm(acc[pp][1]));
            o.y = pk2(sigm(acc[pp][2]), sigm(acc[pp][3]));
            *(uint2*)(Z + (size_t)pl * 64 + dch) = o;
        }
    } else {
        #pragma unroll
        for (int pp = 0; pp < 4; ++pp) {
            int pg = p0 + plb + pt0 + pp;
            float4 hv = *(const float4*)&h[(size_t)pg * 64 + dch];
            int base = (pt0 + pp) * 65 + di * 2;
            a_lds[base]     = pk2(sigm(acc[pp][0]) * hv.x, sigm(acc[pp][1]) * hv.y);
            a_lds[base + 1] = pk2(sigm(acc[pp][2]) * hv.z, sigm(acc[pp][3]) * hv.w);
        }
    }
    for (int i = 0; i < 4; ++i) {           // x into words 32..63
        int id = t + i * 512;
        int p = id >> 5, cw = id & 31;
        float2 v = *(const float2*)(x + (size_t)(p0 + plb + p) * 64 + cw * 2);
        a_lds[p * 65 + 32 + cw] = pk2(v.x, v.y);
    }
    float* wflat = (float*)w_lds;
    for (int i = 0; i < 4; ++i) {           // W1[2] rows 0..127
        int id = t + i * 512;
        int r = id >> 4, d4 = id & 15;
        *(float4*)&wflat[r * 64 + d4 * 4] =
            *(const float4*)(W1f + 2 * 8384 + r * 64 + d4 * 4);
    }
    __syncthreads();
    int pt0b = cg * 8 + pi * 2;
    float pacc[2][4];
    {
        float4 bv = *(const float4*)&b1f[128 + dch];
        #pragma unroll
        for (int pp = 0; pp < 2; ++pp) {
            pacc[pp][0] = bv.x; pacc[pp][1] = bv.y; pacc[pp][2] = bv.z; pacc[pp][3] = bv.w;
        }
    }
    #pragma unroll 2
    for (int cw = 0; cw < 64; ++cw) {
        u32 aw0 = a_lds[(pt0b + 0) * 65 + cw];
        u32 aw1 = a_lds[(pt0b + 1) * 65 + cw];
        float4 w0 = *(float4*)&wflat[(2 * cw) * 64 + dch];
        float4 w1 = *(float4*)&wflat[(2 * cw + 1) * 64 + dch];
        float a00 = bflo(aw0), a01 = bfhi(aw0);
        float a10 = bflo(aw1), a11 = bfhi(aw1);
        pacc[0][0] = fmaf(a00, w0.x, pacc[0][0]); pacc[0][1] = fmaf(a00, w0.y, pacc[0][1]);
        pacc[0][2] = fmaf(a00, w0.z, pacc[0][2]); pacc[0][3] = fmaf(a00, w0.w, pacc[0][3]);
        pacc[0][0] = fmaf(a01, w1.x, pacc[0][0]); pacc[0][1] = fmaf(a01, w1.y, pacc[0][1]);
        pacc[0][2] = fmaf(a01, w1.z, pacc[0][2]); pacc[0][3] = fmaf(a01, w1.w, pacc[0][3]);
        pacc[1][0] = fmaf(a10, w0.x, pacc[1][0]); pacc[1][1] = fmaf(a10, w0.y, pacc[1][1]);
        pacc[1][2] = fmaf(a10, w0.z, pacc[1][2]); pacc[1][3] = fmaf(a10, w0.w, pacc[1][3]);
        pacc[1][0] = fmaf(a11, w1.x, pacc[1][0]); pacc[1][1] = fmaf(a11, w1.y, pacc[1][1]);
        pacc[1][2] = fmaf(a11, w1.z, pacc[1][2]); pacc[1][3] = fmaf(a11, w1.w, pacc[1][3]);
    }
    #pragma unroll
    for (int pp = 0; pp < 2; ++pp) {
        int pl = plb + pt0b + pp;
        uint2 o;
        o.x = pk2(pacc[pp][0], pacc[pp][1]);
        o.y = pk2(pacc[pp][2], pacc[pp][3]);
        *(uint2*)(P2 + (size_t)pl * 64 + dch) = o;
    }
}

// ---------------- K_C: pool2 + mlp2 fused -> out ----------------
__global__ __launch_bounds__(512) void k_fuse2(
    const u16* __restrict__ P2, const float* __restrict__ W1f,
    const int* __restrict__ nidx, const float* __restrict__ ef,
    const float* __restrict__ W2f, const float* __restrict__ b2f,
    const float* __restrict__ W3f, const float* __restrict__ b3f,
    const float* __restrict__ h, const u16* __restrict__ Z,
    float* __restrict__ out, int p0, int full)
{
    __shared__ u32 a_lds[64 * 33];
    __shared__ float w_lds[64 * 64];
    int t = threadIdx.x;
    int plb = swz_plb(blockIdx.x, full);
    int lane = t & 63;
    int cg = __builtin_amdgcn_readfirstlane(t >> 6);
    for (int i = 0; i < 2; ++i) {           // stage W2[2]
        int id = t + i * 512;
        int r = (id >> 4) & 63, d4 = id & 15;
        *(float4*)&w_lds[r * 64 + d4 * 4] =
            *(const float4*)(W2f + 2 * 4096 + r * 64 + d4 * 4);
    }
    {
        const float* W = W1f + 2 * 8384;
        float w0 = W[8192 + lane], w1 = W[8256 + lane], w2 = W[8320 + lane];
        u16* y16 = (u16*)a_lds;
        for (int pp = 0; pp < 8; ++pp) {
            int lp = cg * 8 + pp;
            int pg = p0 + plb + lp;
            int rbase = ((pg >> 13) << 13) - p0;
            const int* ni = nidx + (size_t)pg * KNBR;
            const float* ep = ef + (size_t)pg * KNBR * 3;
            float m = -1e30f;
            #pragma unroll 16
            for (int k = 0; k < KNBR; ++k) {
                int lr = rbase + ni[k];
                float e0 = ep[3 * k], e1 = ep[3 * k + 1], e2 = ep[3 * k + 2];
                float v = bf2f(P2[(size_t)lr * 64 + lane]) + e0 * w0 + e1 * w1 + e2 * w2;
                m = fmaxf(m, v);
            }
            y16[lp * 66 + lane] = f2bf(leaky(m));
        }
    }
    __syncthreads();
    int di = lane & 15, pi = lane >> 4;
    int pt0 = cg * 8 + pi * 2;
    int dch = di * 4;
    float acc[2][4];
    {
        float4 bv = *(const float4*)&b2f[128 + dch];
        #pragma unroll
        for (int pp = 0; pp < 2; ++pp) {
            acc[pp][0] = bv.x; acc[pp][1] = bv.y; acc[pp][2] = bv.z; acc[pp][3] = bv.w;
        }
    }
    #pragma unroll 2
    for (int cw = 0; cw < 32; ++cw) {
        u32 aw0 = a_lds[(pt0 + 0) * 33 + cw];
        u32 aw1 = a_lds[(pt0 + 1) * 33 + cw];
        float4 w0 = *(float4*)&w_lds[(2 * cw) * 64 + dch];
        float4 w1 = *(float4*)&w_lds[(2 * cw + 1) * 64 + dch];
        float a00 = bflo(aw0), a01 = bfhi(aw0);
        float a10 = bflo(aw1), a11 = bfhi(aw1);
        acc[0][0] = fmaf(a00, w0.x, acc[0][0]); acc[0][1] = fmaf(a00, w0.y, acc[0][1]);
        acc[0][2] = fmaf(a00, w0.z, acc[0][2]); acc[0][3] = fmaf(a00, w0.w, acc[0][3]);
        acc[0][0] = fmaf(a01, w1.x, acc[0][0]); acc[0][1] = fmaf(a01, w1.y, acc[0][1]);
        acc[0][2] = fmaf(a01, w1.z, acc[0][2]); acc[0][3] = fmaf(a01, w1.w, acc[0][3]);
        acc[1][0] = fmaf(a10, w0.x, acc[1][0]); acc[1][1] = fmaf(a10, w0.y, acc[1][1]);
        acc[1][2] = fmaf(a10, w0.z, acc[1][2]); acc[1][3] = fmaf(a10, w0.w, acc[1][3]);
        acc[1][0] = fmaf(a11, w1.x, acc[1][0]); acc[1][1] = fmaf(a11, w1.y, acc[1][1]);
        acc[1][2] = fmaf(a11, w1.z, acc[1][2]); acc[1][3] = fmaf(a11, w1.w, acc[1][3]);
    }
    __syncthreads();
    #pragma unroll
    for (int pp = 0; pp < 2; ++pp) {
        int base = (pt0 + pp) * 33 + di * 2;
        a_lds[base]     = pk2(leaky(acc[pp][0]), leaky(acc[pp][1]));
        a_lds[base + 1] = pk2(leaky(acc[pp][2]), leaky(acc[pp][3]));
    }
    for (int i = 0; i < 2; ++i) {           // restage W3[2]
        int id = t + i * 512;
        int r = (id >> 4) & 63, d4 = id & 15;
        *(float4*)&w_lds[r * 64 + d4 * 4] =
            *(const float4*)(W3f + 2 * 4096 + r * 64 + d4 * 4);
    }
    __syncthreads();
    {
        float4 bv = *(const float4*)&b3f[128 + dch];
        #pragma unroll
        for (int pp = 0; pp < 2; ++pp) {
            acc[pp][0] = bv.x; acc[pp][1] = bv.y; acc[pp][2] = bv.z; acc[pp][3] = bv.w;
        }
    }
    #pragma unroll 2
    for (int cw = 0; cw < 32; ++cw) {
        u32 aw0 = a_lds[(pt0 + 0) * 33 + cw];
        u32 aw1 = a_lds[(pt0 + 1) * 33 + cw];
        float4 w0 = *(float4*)&w_lds[(2 * cw) * 64 + dch];
        float4 w1 = *(float4*)&w_lds[(2 * cw + 1) * 64 + dch];
        float a00 = bflo(aw0), a01 = bfhi(aw0);
        float a10 = bflo(aw1), a11 = bfhi(aw1);
        acc[0][0] = fmaf(a00, w0.x, acc[0][0]); acc[0][1] = fmaf(a00, w0.y, acc[0][1]);
        acc[0][2] = fmaf(a00, w0.z, acc[0][2]); acc[0][3] = fmaf(a00, w0.w, acc[0][3]);
        acc[0][0] = fmaf(a01, w1.x, acc[0][0]); acc[0][1] = fmaf(a01, w1.y, acc[0][1]);
        acc[0][2] = fmaf(a01, w1.z, acc[0][2]); acc[0][3] = fmaf(a01, w1.w, acc[0][3]);
        acc[1][0] = fmaf(a10, w0.x, acc[1][0]); acc[1][1] = fmaf(a10, w0.y, acc[1][1]);
        acc[1][2] = fmaf(a10, w0.z, acc[1][2]); acc[1][3] = fmaf(a10, w0.w, acc[1][3]);
        acc[1][0] = fmaf(a11, w1.x, acc[1][0]); acc[1][1] = fmaf(a11, w1.y, acc[1][1]);
        acc[1][2] = fmaf(a11, w1.z, acc[1][2]); acc[1][3] = fmaf(a11, w1.w, acc[1][3]);
    }
    #pragma unroll
    for (int pp = 0; pp < 2; ++pp) {
        int pl = plb + pt0 + pp;
        int pg = p0 + pl;
        float4 hv = *(const float4*)&h[(size_t)pg * 64 + dch];
        uint2 zw = *(const uint2*)(Z + (size_t)pl * 64 + dch);
        float z0 = bflo(zw.x), z1 = bfhi(zw.x), z2 = bflo(zw.y), z3 = bfhi(zw.y);
        float4 o;
        o.x = (1.f - z0) * hv.x + z0 * tanhf(acc[pp][0]);
        o.y = (1.f - z1) * hv.y + z1 * tanhf(acc[pp][1]);
        o.z = (1.f - z2) * hv.z + z2 * tanhf(acc[pp][2]);
        o.w = (1.f - z3) * hv.w + z3 * tanhf(acc[pp][3]);
        *(float4*)&out[(size_t)pg * 64 + dch] = o;
    }
}

extern "C" void kernel_launch(void* const* d_in, const int* in_sizes, int n_in,
                              void* d_out, int out_size, void* d_ws, size_t ws_size,
                              hipStream_t stream)
{
    const float* h  = (const float*)d_in[0];
    const float* x  = (const float*)d_in[1];
    // d_in[2] = c (unused by the reference)
    const float* W1 = (const float*)d_in[3];
    const float* b1 = (const float*)d_in[4];
    const float* W2 = (const float*)d_in[5];
    const float* b2 = (const float*)d_in[6];
    const float* W3 = (const float*)d_in[7];
    const float* b3 = (const float*)d_in[8];
    const int* nidx = (const int*)d_in[9];
    const float* ef = (const float*)d_in[10];
    float* out = (float*)d_out;

    char* wsb = (char*)d_ws;
    size_t PN = (ws_size >= 32768ull * 512ull) ? 32768 : 8192;
    int passes = (int)(32768 / PN);
    int full = (PN == 32768) ? 1 : 0;

    u32* P01 = (u32*)wsb;                       // [PN][64] u32 (gate-interleaved bf16 pair)
    u16* Z   = (u16*)(wsb + PN * 256);          // [PN][64] bf16
    u16* P2  = (u16*)(wsb + PN * 384);          // [PN][64] bf16

    for (int s = 0; s < passes; ++s) {
        int p0 = (int)(s * PN);
        dim3 g((unsigned)(PN / 64));
        k_gemm_p01<<<g, 512, 0, stream>>>(h, x, W1, b1, P01, p0, full);
        k_fuse01  <<<g, 512, 0, stream>>>(P01, W1, nidx, ef, h, x,
                                          W2, b2, W3, b3, b1, Z, P2, p0, full);
        k_fuse2   <<<g, 512, 0, stream>>>(P2, W1, nidx, ef,
                                          W2, b2, W3, b3, h, Z, out, p0, full);
    }
}

// Round 10
// 182.829 us; speedup vs baseline: 1.0935x; 1.0935x over previous
//
#include <hip/hip_runtime.h>
#include <math.h>

typedef unsigned short u16;
typedef unsigned int u32;
typedef __attribute__((ext_vector_type(8))) short s8v;   // 8 bf16 (4 VGPRs)
typedef __attribute__((ext_vector_type(4))) float f4v;   // MFMA acc

#define KNBR 32
#define MFMA16(a, b, c) __builtin_amdgcn_mfma_f32_16x16x32_bf16((a), (b), (c), 0, 0, 0)

__device__ __forceinline__ float bf2f(u16 u) { return __uint_as_float((u32)u << 16); }
__device__ __forceinline__ float bflo(u32 u) { return __uint_as_float(u << 16); }
__device__ __forceinline__ float bfhi(u32 u) { return __uint_as_float(u & 0xffff0000u); }
__device__ __forceinline__ u16 f2bf(float f) {
    u32 u = __float_as_uint(f);
    return (u16)((u + 0x7fffu + ((u >> 16) & 1u)) >> 16);
}
__device__ __forceinline__ u32 pk2(float a, float b) {
    return (u32)f2bf(a) | ((u32)f2bf(b) << 16);
}
__device__ __forceinline__ float leaky(float v) { return v >= 0.f ? v : 0.1f * v; }
__device__ __forceinline__ float sigm(float v) { return 1.f / (1.f + expf(-v)); }

// XCD-batch swizzle (keeps each batch's P01/P2 segment in one XCD pair's L2).
__device__ __forceinline__ int swz_plb(int b, int full) {
    if (!full) return b << 6;
    int xcd = b & 7;
    int within = ((b >> 3) << 1) | (xcd & 1);
    return ((xcd >> 1) << 13) + (within << 6);
}

// W1: [3][131][64] fp32 (g*8384 + c*64 + d); W2/W3: [3][64][64]; biases [3][64].
// P01: u32 [row][64ch] = pk2(gate0, gate1). Z: u16 [row][64]. P2: f32 [row][64].
// MFMA frags: A[m=lane&15][k=quad*8+j]; B[k=quad*8+j][n=lane&15];
// D: col(n)=lane&15, row(m)=quad*4+reg.

// ---------------- K_A: P01 = [h|x] @ W1[0,1] + b1 (both gates, MFMA) ----------------
__global__ __launch_bounds__(512) void k_gemm_p01(
    const float* __restrict__ h, const float* __restrict__ x,
    const float* __restrict__ W1f, const float* __restrict__ b1f,
    u32* __restrict__ P01, int p0, int full)
{
    __shared__ u32 a_lds[64 * 68];          // act bf16-pairs along K=128 (64 words + pad)
    __shared__ u32 wb[2 * 64 * 68];         // B-frags: [(g*64+n)*68 + kpair]
    int t = threadIdx.x;
    int plb = swz_plb(blockIdx.x, full);
    int pgb = p0 + plb;
    for (int i = 0; i < 8; ++i) {           // activations: 4096 words
        int id = t + i * 512;
        int p = id >> 6, cw = id & 63;
        const float* src = (cw < 32) ? (h + (size_t)(pgb + p) * 64 + cw * 2)
                                     : (x + (size_t)(pgb + p) * 64 + (cw - 32) * 2);
        float2 v = *(const float2*)src;
        a_lds[p * 68 + cw] = pk2(v.x, v.y);
    }
    for (int i = 0; i < 16; ++i) {          // W1 gates 0,1 -> B-frags: 8192 words
        int id = t + i * 512;
        int g = id >> 12, kp = (id >> 6) & 63, n = id & 63;
        float w0 = W1f[g * 8384 + kp * 128 + n];
        float w1 = W1f[g * 8384 + kp * 128 + 64 + n];
        wb[(g * 64 + n) * 68 + kp] = pk2(w0, w1);
    }
    __syncthreads();
    int lane = t & 63;
    int w = __builtin_amdgcn_readfirstlane(t >> 6);
    int m = w & 3, npair = w >> 2;          // m-tile 0..3, n-pair 0..1
    int quad = lane >> 4, l15 = lane & 15;
    f4v acc[2][2];                          // [gate][nt]
    #pragma unroll
    for (int g = 0; g < 2; ++g)
        #pragma unroll
        for (int nt = 0; nt < 2; ++nt) {
            float b = b1f[g * 64 + (npair * 2 + nt) * 16 + l15];
            acc[g][nt] = (f4v){b, b, b, b};
        }
    #pragma unroll
    for (int kb = 0; kb < 4; ++kb) {
        s8v af = *(const s8v*)&a_lds[(m * 16 + l15) * 68 + kb * 16 + quad * 4];
        #pragma unroll
        for (int g = 0; g < 2; ++g)
            #pragma unroll
            for (int nt = 0; nt < 2; ++nt) {
                s8v bf = *(const s8v*)&wb[(g * 64 + (npair * 2 + nt) * 16 + l15) * 68
                                          + kb * 16 + quad * 4];
                acc[g][nt] = MFMA16(af, bf, acc[g][nt]);
            }
    }
    #pragma unroll
    for (int nt = 0; nt < 2; ++nt)
        #pragma unroll
        for (int r = 0; r < 4; ++r) {
            int pt = m * 16 + quad * 4 + r;
            int ch = (npair * 2 + nt) * 16 + l15;
            P01[(size_t)(plb + pt) * 64 + ch] = pk2(acc[0][nt][r], acc[1][nt][r]);
        }
}

// ---------------- K_B: pool01 + MLP(g0,g1) + gemm_p2, MFMA dense ----------------
__global__ __launch_bounds__(512) void k_fuse01(
    const u32* __restrict__ P01, const float* __restrict__ W1f,
    const int* __restrict__ nidx, const float* __restrict__ ef,
    const float* __restrict__ h, const float* __restrict__ x,
    const float* __restrict__ W2f, const float* __restrict__ b2f,
    const float* __restrict__ W3f, const float* __restrict__ b3f,
    const float* __restrict__ b1f,
    u16* __restrict__ Z, float* __restrict__ P2, int p0, int full)
{
    __shared__ u32 a_lds[64 * 68];          // Y/t (u16 idx: pt*136 + g*64 + ch), later RH|x
    __shared__ u32 wb[4608];                // W2/W3 frags (2*64*36) or W1[2] frags (64*68)
    int t = threadIdx.x;
    int plb = swz_plb(blockIdx.x, full);
    int lane = t & 63;
    int w = __builtin_amdgcn_readfirstlane(t >> 6);
    int quad = lane >> 4, l15 = lane & 15;
    u16* y16 = (u16*)a_lds;

    for (int i = 0; i < 8; ++i) {           // stage W2 B-frags (both gates): 4096 words
        int id = t + i * 512;
        int g = id >> 11, kp = (id >> 6) & 31, n = id & 63;
        float w0 = W2f[g * 4096 + kp * 128 + n];
        float w1 = W2f[g * 4096 + kp * 128 + 64 + n];
        wb[(g * 64 + n) * 36 + kp] = pk2(w0, w1);
    }
    {   // pool: wave w pools points w*8..w*8+7 (lane = channel)
        float w00 = W1f[8192 + lane], w01 = W1f[8256 + lane], w02 = W1f[8320 + lane];
        float w10 = W1f[16576 + lane], w11 = W1f[16640 + lane], w12 = W1f[16704 + lane];
        for (int pp = 0; pp < 8; ++pp) {
            int lp = w * 8 + pp;
            int pg = p0 + plb + lp;
            int rbase = ((pg >> 13) << 13) - p0;
            const int* ni = nidx + (size_t)pg * KNBR;
            const float* ep = ef + (size_t)pg * KNBR * 3;
            float m0 = -1e30f, m1 = -1e30f;
            #pragma unroll 16
            for (int k = 0; k < KNBR; ++k) {
                int lr = rbase + ni[k];
                u32 gv = P01[(size_t)lr * 64 + lane];
                float e0 = ep[3 * k], e1 = ep[3 * k + 1], e2 = ep[3 * k + 2];
                m0 = fmaxf(m0, bflo(gv) + e0 * w00 + e1 * w01 + e2 * w02);
                m1 = fmaxf(m1, bfhi(gv) + e0 * w10 + e1 * w11 + e2 * w12);
            }
            y16[lp * 136 + lane]      = f2bf(leaky(m0));
            y16[lp * 136 + 64 + lane] = f2bf(leaky(m1));
        }
    }
    __syncthreads();
    int m = w & 3, g = w >> 2;              // wave = (m-tile, gate)
    f4v acc[4];
    #pragma unroll
    for (int nt = 0; nt < 4; ++nt) {
        float b = b2f[g * 64 + nt * 16 + l15];
        acc[nt] = (f4v){b, b, b, b};
    }
    #pragma unroll
    for (int kb = 0; kb < 2; ++kb) {        // L1: K=64 (gate's Y)
        s8v af = *(const s8v*)&a_lds[(m * 16 + l15) * 68 + g * 32 + kb * 16 + quad * 4];
        #pragma unroll
        for (int nt = 0; nt < 4; ++nt) {
            s8v bf = *(const s8v*)&wb[(g * 64 + nt * 16 + l15) * 36 + kb * 16 + quad * 4];
            acc[nt] = MFMA16(af, bf, acc[nt]);
        }
    }
    #pragma unroll
    for (int nt = 0; nt < 4; ++nt)          // t -> same LDS slots (own wave's region)
        #pragma unroll
        for (int r = 0; r < 4; ++r)
            y16[(m * 16 + quad * 4 + r) * 136 + g * 64 + nt * 16 + l15] =
                f2bf(leaky(acc[nt][r]));
    __syncthreads();
    for (int i = 0; i < 8; ++i) {           // restage W3 B-frags
        int id = t + i * 512;
        int gg = id >> 11, kp = (id >> 6) & 31, n = id & 63;
        float w0 = W3f[gg * 4096 + kp * 128 + n];
        float w1 = W3f[gg * 4096 + kp * 128 + 64 + n];
        wb[(gg * 64 + n) * 36 + kp] = pk2(w0, w1);
    }
    __syncthreads();
    #pragma unroll
    for (int nt = 0; nt < 4; ++nt) {
        float b = b3f[g * 64 + nt * 16 + l15];
        acc[nt] = (f4v){b, b, b, b};
    }
    #pragma unroll
    for (int kb = 0; kb < 2; ++kb) {        // L2
        s8v af = *(const s8v*)&a_lds[(m * 16 + l15) * 68 + g * 32 + kb * 16 + quad * 4];
        #pragma unroll
        for (int nt = 0; nt < 4; ++nt) {
            s8v bf = *(const s8v*)&wb[(g * 64 + nt * 16 + l15) * 36 + kb * 16 + quad * 4];
            acc[nt] = MFMA16(af, bf, acc[nt]);
        }
    }
    __syncthreads();                        // all L2 LDS reads done
    if (g == 0) {                           // Z -> global
        #pragma unroll
        for (int nt = 0; nt < 4; ++nt)
            #pragma unroll
            for (int r = 0; r < 4; ++r) {
                int pt = m * 16 + quad * 4 + r;
                int ch = nt * 16 + l15;
                Z[(size_t)(plb + pt) * 64 + ch] = f2bf(sigm(acc[nt][r]));
            }
    } else {                                // RH -> a_lds words 0..31 (K pairs 0..63)
        #pragma unroll
        for (int nt = 0; nt < 4; ++nt)
            #pragma unroll
            for (int r = 0; r < 4; ++r) {
                int pt = m * 16 + quad * 4 + r;
                int ch = nt * 16 + l15;
                float hv = h[(size_t)(p0 + plb + pt) * 64 + ch];
                y16[pt * 136 + ch] = f2bf(sigm(acc[nt][r]) * hv);
            }
    }
    for (int i = 0; i < 4; ++i) {           // x -> a_lds words 32..63
        int id = t + i * 512;
        int p = id >> 5, cw = id & 31;
        float2 v = *(const float2*)(x + (size_t)(p0 + plb + p) * 64 + cw * 2);
        a_lds[p * 68 + 32 + cw] = pk2(v.x, v.y);
    }
    for (int i = 0; i < 8; ++i) {           // W1[2] B-frags: 4096 words, stride 68
        int id = t + i * 512;
        int kp = (id >> 6) & 63, n = id & 63;
        float w0 = W1f[2 * 8384 + kp * 128 + n];
        float w1 = W1f[2 * 8384 + kp * 128 + 64 + n];
        wb[n * 68 + kp] = pk2(w0, w1);
    }
    __syncthreads();
    int nh = w >> 2;                        // gemm_p2: wave = (m, n-half)
    f4v pacc[2];
    #pragma unroll
    for (int nt = 0; nt < 2; ++nt) {
        float b = b1f[128 + (nh * 2 + nt) * 16 + l15];
        pacc[nt] = (f4v){b, b, b, b};
    }
    #pragma unroll
    for (int kb = 0; kb < 4; ++kb) {        // K=128 ([RH|x])
        s8v af = *(const s8v*)&a_lds[(m * 16 + l15) * 68 + kb * 16 + quad * 4];
        #pragma unroll
        for (int nt = 0; nt < 2; ++nt) {
            s8v bf = *(const s8v*)&wb[((nh * 2 + nt) * 16 + l15) * 68 + kb * 16 + quad * 4];
            pacc[nt] = MFMA16(af, bf, pacc[nt]);
        }
    }
    #pragma unroll
    for (int nt = 0; nt < 2; ++nt)
        #pragma unroll
        for (int r = 0; r < 4; ++r) {
            int pt = m * 16 + quad * 4 + r;
            int ch = (nh * 2 + nt) * 16 + l15;
            P2[(size_t)(plb + pt) * 64 + ch] = pacc[nt][r];
        }
}

// ---------------- K_C: pool2 + MLP(g2) + GRU epilogue, MFMA dense ----------------
__global__ __launch_bounds__(512) void k_fuse2(
    const float* __restrict__ P2, const float* __restrict__ W1f,
    const int* __restrict__ nidx, const float* __restrict__ ef,
    const float* __restrict__ W2f, const float* __restrict__ b2f,
    const float* __restrict__ W3f, const float* __restrict__ b3f,
    const float* __restrict__ h, const u16* __restrict__ Z,
    float* __restrict__ out, int p0, int full)
{
    __shared__ u32 a_lds[64 * 36];          // Y/t (u16 idx: pt*72 + ch)
    __shared__ u32 wb[64 * 36];             // W2[2] then W3[2] B-frags
    int t = threadIdx.x;
    int plb = swz_plb(blockIdx.x, full);
    int lane = t & 63;
    int w = __builtin_amdgcn_readfirstlane(t >> 6);
    int quad = lane >> 4, l15 = lane & 15;
    u16* y16 = (u16*)a_lds;

    for (int i = 0; i < 4; ++i) {           // stage W2[2] B-frags: 2048 words
        int id = t + i * 512;
        int kp = (id >> 6) & 31, n = id & 63;
        float w0 = W2f[2 * 4096 + kp * 128 + n];
        float w1 = W2f[2 * 4096 + kp * 128 + 64 + n];
        wb[n * 36 + kp] = pk2(w0, w1);
    }
    {   // pool2
        const float* W = W1f + 2 * 8384;
        float w0 = W[8192 + lane], w1 = W[8256 + lane], w2 = W[8320 + lane];
        for (int pp = 0; pp < 8; ++pp) {
            int lp = w * 8 + pp;
            int pg = p0 + plb + lp;
            int rbase = ((pg >> 13) << 13) - p0;
            const int* ni = nidx + (size_t)pg * KNBR;
            const float* ep = ef + (size_t)pg * KNBR * 3;
            float m = -1e30f;
            #pragma unroll 16
            for (int k = 0; k < KNBR; ++k) {
                int lr = rbase + ni[k];
                float e0 = ep[3 * k], e1 = ep[3 * k + 1], e2 = ep[3 * k + 2];
                float v = P2[(size_t)lr * 64 + lane] + e0 * w0 + e1 * w1 + e2 * w2;
                m = fmaxf(m, v);
            }
            y16[lp * 72 + lane] = f2bf(leaky(m));
        }
    }
    __syncthreads();
    int m = w & 3, nh = w >> 2;
    f4v acc[2];
    #pragma unroll
    for (int nt = 0; nt < 2; ++nt) {
        float b = b2f[128 + (nh * 2 + nt) * 16 + l15];
        acc[nt] = (f4v){b, b, b, b};
    }
    #pragma unroll
    for (int kb = 0; kb < 2; ++kb) {        // L1: K=64
        s8v af = *(const s8v*)&a_lds[(m * 16 + l15) * 36 + kb * 16 + quad * 4];
        #pragma unroll
        for (int nt = 0; nt < 2; ++nt) {
            s8v bf = *(const s8v*)&wb[((nh * 2 + nt) * 16 + l15) * 36 + kb * 16 + quad * 4];
            acc[nt] = MFMA16(af, bf, acc[nt]);
        }
    }
    __syncthreads();                        // all L1 reads done before t overwrite visible x-wave
    #pragma unroll
    for (int nt = 0; nt < 2; ++nt)
        #pragma unroll
        for (int r = 0; r < 4; ++r)
            y16[(m * 16 + quad * 4 + r) * 72 + (nh * 2 + nt) * 16 + l15] =
                f2bf(leaky(acc[nt][r]));
    for (int i = 0; i < 4; ++i) {           // restage W3[2]
        int id = t + i * 512;
        int kp = (id >> 6) & 31, n = id & 63;
        float w0 = W3f[2 * 4096 + kp * 128 + n];
        float w1 = W3f[2 * 4096 + kp * 128 + 64 + n];
        wb[n * 36 + kp] = pk2(w0, w1);
    }
    __syncthreads();
    #pragma unroll
    for (int nt = 0; nt < 2; ++nt) {
        float b = b3f[128 + (nh * 2 + nt) * 16 + l15];
        acc[nt] = (f4v){b, b, b, b};
    }
    #pragma unroll
    for (int kb = 0; kb < 2; ++kb) {        // L2
        s8v af = *(const s8v*)&a_lds[(m * 16 + l15) * 36 + kb * 16 + quad * 4];
        #pragma unroll
        for (int nt = 0; nt < 2; ++nt) {
            s8v bf = *(const s8v*)&wb[((nh * 2 + nt) * 16 + l15) * 36 + kb * 16 + quad * 4];
            acc[nt] = MFMA16(af, bf, acc[nt]);
        }
    }
    #pragma unroll
    for (int nt = 0; nt < 2; ++nt)
        #pragma unroll
        for (int r = 0; r < 4; ++r) {
            int pt = m * 16 + quad * 4 + r;
            int ch = (nh * 2 + nt) * 16 + l15;
            int pl = plb + pt;
            int pg = p0 + pl;
            float z = bf2f(Z[(size_t)pl * 64 + ch]);
            float hv = h[(size_t)pg * 64 + ch];
            out[(size_t)pg * 64 + ch] = (1.f - z) * hv + z * tanhf(acc[nt][r]);
        }
}

extern "C" void kernel_launch(void* const* d_in, const int* in_sizes, int n_in,
                              void* d_out, int out_size, void* d_ws, size_t ws_size,
                              hipStream_t stream)
{
    const float* h  = (const float*)d_in[0];
    const float* x  = (const float*)d_in[1];
    // d_in[2] = c (unused by the reference)
    const float* W1 = (const float*)d_in[3];
    const float* b1 = (const float*)d_in[4];
    const float* W2 = (const float*)d_in[5];
    const float* b2 = (const float*)d_in[6];
    const float* W3 = (const float*)d_in[7];
    const float* b3 = (const float*)d_in[8];
    const int* nidx = (const int*)d_in[9];
    const float* ef = (const float*)d_in[10];
    float* out = (float*)d_out;

    char* wsb = (char*)d_ws;
    size_t PN = (ws_size >= 32768ull * 640ull) ? 32768 : 8192;
    int passes = (int)(32768 / PN);
    int full = (PN == 32768) ? 1 : 0;

    u32* P01  = (u32*)wsb;                  // [PN][64] u32 (gate-interleaved bf16 pair)
    u16* Z    = (u16*)(wsb + PN * 256);     // [PN][64] bf16
    float* P2 = (float*)(wsb + PN * 384);   // [PN][64] f32

    for (int s = 0; s < passes; ++s) {
        int p0 = (int)(s * PN);
        dim3 g((unsigned)(PN / 64));
        k_gemm_p01<<<g, 512, 0, stream>>>(h, x, W1, b1, P01, p0, full);
        k_fuse01  <<<g, 512, 0, stream>>>(P01, W1, nidx, ef, h, x,
                                          W2, b2, W3, b3, b1, Z, P2, p0, full);
        k_fuse2   <<<g, 512, 0, stream>>>(P2, W1, nidx, ef,
                                          W2, b2, W3, b3, h, Z, out, p0, full);
    }
}